// Round 6
// baseline (362.193 us; speedup 1.0000x reference)
//
#include <hip/hip_runtime.h>
#include <math.h>

// TopKRouter: x[16384,2048] fp32, W[64,2048] fp32
// out: [0..32767] top2 indices (as float), [32768..65535] gates, [65536] aux
// Split-fp16 MFMA (3-term: xh*wh + xh*wl + xl*wh; xl*wl ~4e-8, dropped).
// No LDS / no barriers in the K-loop: A-frags loaded per-lane from x,
// W-frags streamed frag-linear from L2 (prep kernel), deep vmcnt pipeline.
#define NTOK 16384
#define DDIM 2048
#define NEXP 64
#define TM   32                 // tokens per block (2 MFMA M-tiles)
#define NBLK (NTOK / TM)        // 512 blocks -> 2 blocks/CU
#define NS   64                 // K32 MFMA steps

typedef _Float16 half8v __attribute__((ext_vector_type(8)));
typedef float    f32x4  __attribute__((ext_vector_type(4)));

#define MFMA16(a, b, c) __builtin_amdgcn_mfma_f32_16x16x32_f16((a), (b), (c), 0, 0, 0)

// W prep: fp32 -> (wh, wl) fp16 in MFMA-B fragment-linear layout (r5-verified):
// element (e,k): S=k>>5, nb=e>>4, nl=e&15, q=(k>>3)&3, j=k&7
// off = S*2048 + nb*512 + q*128 + nl*8 + j
__global__ __launch_bounds__(256) void prep_kernel(const float* __restrict__ W,
                                                   _Float16* __restrict__ Wh,
                                                   _Float16* __restrict__ Wl,
                                                   float* __restrict__ accg) {
    int idx = blockIdx.x * 256 + threadIdx.x;       // 512 blocks -> 131072
    int e = idx >> 11, k = idx & 2047;
    float w = W[idx];
    _Float16 h = (_Float16)w;
    _Float16 l = (_Float16)(w - (float)h);
    int S = k >> 5, nb = e >> 4, nl = e & 15, q = (k >> 3) & 3, j = k & 7;
    size_t off = (size_t)S * 2048 + nb * 512 + q * 128 + nl * 8 + j;
    Wh[off] = h;
    Wl[off] = l;
    if (blockIdx.x == 0 && threadIdx.x < 128) accg[threadIdx.x] = 0.0f;
}

__device__ inline void cvt8(const float4* f, half8v& h, half8v& l) {
    const float* p = (const float*)f;   // 8 floats
    #pragma unroll
    for (int i = 0; i < 8; ++i) {
        _Float16 hi = (_Float16)p[i];
        h[i] = hi;
        l[i] = (_Float16)(p[i] - (float)hi);
    }
}

__global__ __launch_bounds__(256) void router_kernel(
    const float* __restrict__ x, const _Float16* __restrict__ Wh,
    const _Float16* __restrict__ Wl, float* __restrict__ accg,
    float* __restrict__ out)
{
    __shared__ float lgt[TM][NEXP + 1];   // epilogue only
    __shared__ float cnt[NEXP];

    const int tid  = threadIdx.x;
    const int lane = tid & 63;
    const int wv   = __builtin_amdgcn_readfirstlane(tid >> 6);  // expert block 0..3
    const int m0   = blockIdx.x * TM;

    if (tid < NEXP) cnt[tid] = 0.0f;

    // A-frag per-lane addressing: m = lane&15 (token), k-group = (lane>>4)*8
    const int mrow = lane & 15;
    const int kg   = (lane >> 4) * 8;
    const float* ax0 = x + (size_t)(m0 + mrow) * DDIM + kg;   // M-tile 0
    const float* ax1 = ax0 + (size_t)16 * DDIM;               // M-tile 1

    // W-frag pointers (frag-linear, L2-hot)
    const _Float16* whp = Wh + wv * 512 + lane * 8;
    const _Float16* wlp = Wl + wv * 512 + lane * 8;

    f32x4 acc0 = {0.f, 0.f, 0.f, 0.f};
    f32x4 acc1 = {0.f, 0.f, 0.f, 0.f};

    float4 fa[4][2][2];      // A prefetch: [slot][tile][half-of-8] depth 4
    half8v wbh[2], wbl[2];   // W prefetch: depth 2

    #pragma unroll
    for (int s = 0; s < 4; ++s) {
        fa[s][0][0] = *(const float4*)(ax0 + s * 32);
        fa[s][0][1] = *(const float4*)(ax0 + s * 32 + 4);
        fa[s][1][0] = *(const float4*)(ax1 + s * 32);
        fa[s][1][1] = *(const float4*)(ax1 + s * 32 + 4);
    }
    #pragma unroll
    for (int s = 0; s < 2; ++s) {
        wbh[s] = *(const half8v*)(whp + (size_t)s * 2048);
        wbl[s] = *(const half8v*)(wlp + (size_t)s * 2048);
    }

    for (int mc = 0; mc < NS / 4; ++mc) {
        #pragma unroll
        for (int sub = 0; sub < 4; ++sub) {
            const int s = mc * 4 + sub;
            // consume A slot (vmcnt wait here; loads issued 4 steps ago)
            half8v a0h, a0l, a1h, a1l;
            cvt8(fa[sub][0], a0h, a0l);
            cvt8(fa[sub][1], a1h, a1l);
            half8v bh = wbh[sub & 1], bl = wbl[sub & 1];
            // prefetch A for step s+4 into this slot (wrap reload harmless)
            const int sa = (s + 4) & (NS - 1);
            fa[sub][0][0] = *(const float4*)(ax0 + sa * 32);
            fa[sub][0][1] = *(const float4*)(ax0 + sa * 32 + 4);
            fa[sub][1][0] = *(const float4*)(ax1 + sa * 32);
            fa[sub][1][1] = *(const float4*)(ax1 + sa * 32 + 4);
            // prefetch W for step s+2
            const int sw = (s + 2) & (NS - 1);
            wbh[sub & 1] = *(const half8v*)(whp + (size_t)sw * 2048);
            wbl[sub & 1] = *(const half8v*)(wlp + (size_t)sw * 2048);
            // 6 MFMAs: two independent 3-chains
            acc0 = MFMA16(a0l, bh, acc0);
            acc0 = MFMA16(a0h, bl, acc0);
            acc0 = MFMA16(a0h, bh, acc0);
            acc1 = MFMA16(a1l, bh, acc1);
            acc1 = MFMA16(a1h, bl, acc1);
            acc1 = MFMA16(a1h, bh, acc1);
        }
    }

    // ---- C layout: row m=(lane>>4)*4+r, col n=lane&15 (m89/r5-verified) ----
    {
        const int q  = lane >> 4;
        const int nl = lane & 15;
        #pragma unroll
        for (int r = 0; r < 4; ++r) {
            lgt[q * 4 + r][wv * 16 + nl]      = acc0[r];
            lgt[16 + q * 4 + r][wv * 16 + nl] = acc1[r];
        }
    }
    __syncthreads();

    // ---- softmax + top-2: 8 threads per token (32 tok x 8 = 256 thr) ----
    const int m = tid >> 3;
    const int j = tid & 7;
    float l[8];
    #pragma unroll
    for (int i = 0; i < 8; ++i) l[i] = lgt[m][j * 8 + i];

    float mx = l[0];
    #pragma unroll
    for (int i = 1; i < 8; ++i) mx = fmaxf(mx, l[i]);
    #pragma unroll
    for (int off = 1; off < 8; off <<= 1) mx = fmaxf(mx, __shfl_xor(mx, off, 8));

    float ev[8];
    float zs = 0.f;
    float v1 = -INFINITY, v2 = -INFINITY;
    int i1 = 0, i2 = 0;
    #pragma unroll
    for (int i = 0; i < 8; ++i) {
        ev[i] = __expf(l[i] - mx);
        zs += ev[i];
        int e = j * 8 + i;
        if (l[i] > v1)      { v2 = v1; i2 = i1; v1 = l[i]; i1 = e; }
        else if (l[i] > v2) { v2 = l[i]; i2 = e; }
    }
    #pragma unroll
    for (int off = 1; off < 8; off <<= 1) zs += __shfl_xor(zs, off, 8);

    // merge top-2 across 8 lanes (value desc, index asc on ties = lax.top_k)
    #pragma unroll
    for (int off = 1; off < 8; off <<= 1) {
        float ov1 = __shfl_xor(v1, off, 8);
        int   oi1 = __shfl_xor(i1, off, 8);
        float ov2 = __shfl_xor(v2, off, 8);
        int   oi2 = __shfl_xor(i2, off, 8);
        bool afirst = (v1 > ov1) || (v1 == ov1 && i1 < oi1);
        if (afirst) {
            bool t = (v2 > ov1) || (v2 == ov1 && i2 < oi1);
            v2 = t ? v2 : ov1;
            i2 = t ? i2 : oi1;
        } else {
            bool t = (ov2 > v1) || (ov2 == v1 && oi2 < i1);
            v2 = t ? ov2 : v1;
            i2 = t ? oi2 : i1;
            v1 = ov1;
            i1 = oi1;
        }
    }

    const float invz = 1.0f / zs;
    if (j == 0) {
        float p1 = invz;                      // v1 == mx exactly
        float p2 = __expf(v2 - mx) * invz;
        float sden = p1 + p2 + 1e-9f;
        int tok = m0 + m;
        out[tok * 2 + 0] = (float)i1;
        out[tok * 2 + 1] = (float)i2;
        out[32768 + tok * 2 + 0] = p1 / sden;
        out[32768 + tok * 2 + 1] = p2 / sden;
        atomicAdd(&cnt[i1], 1.0f);
        atomicAdd(&cnt[i2], 1.0f);
    }

    // probs writeback (own slots only)
    #pragma unroll
    for (int i = 0; i < 8; ++i) lgt[m][j * 8 + i] = ev[i] * invz;
    __syncthreads();

    // global accumulators (accg zeroed by prep each launch)
    if (tid < NEXP) {
        atomicAdd(&accg[tid], cnt[tid]);
    } else if (tid < 128) {
        int e = tid - 64;
        float s = 0.f;
        #pragma unroll 8
        for (int t = 0; t < TM; ++t) s += lgt[t][e];
        atomicAdd(&accg[64 + e], s);
    }
}

__global__ void finalize_kernel(const float* __restrict__ accg,
                                float* __restrict__ out)
{
    int t = threadIdx.x;   // 64 threads
    float c = accg[t];
    float p = accg[64 + t];
    float term = (c / (float)(NTOK * 2)) * (p / (float)NTOK);
    #pragma unroll
    for (int off = 1; off < 64; off <<= 1) term += __shfl_xor(term, off, 64);
    if (t == 0) out[65536] = 0.01f * (float)NEXP * term;
}

extern "C" void kernel_launch(void* const* d_in, const int* in_sizes, int n_in,
                              void* d_out, int out_size, void* d_ws, size_t ws_size,
                              hipStream_t stream) {
    const float* x = (const float*)d_in[0];   // [4,4096,2048]
    const float* W = (const float*)d_in[1];   // [64,2048]
    float* out  = (float*)d_out;              // 65537 floats
    float* accg = (float*)d_ws;               // 128 floats
    _Float16* Wh = (_Float16*)(accg + 128);   // 131072 halfs (256 KB)
    _Float16* Wl = Wh + (size_t)DDIM * NEXP;  // 131072 halfs (256 KB)

    prep_kernel<<<512, 256, 0, stream>>>(W, Wh, Wl, accg);
    router_kernel<<<NBLK, 256, 0, stream>>>(x, Wh, Wl, accg, out);
    finalize_kernel<<<1, 64, 0, stream>>>(accg, out);
}

// Round 7
// 215.587 us; speedup vs baseline: 1.6800x; 1.6800x over previous
//
#include <hip/hip_runtime.h>
#include <math.h>

// TopKRouter: x[16384,2048] fp32, W[64,2048] fp32
// out: [0..32767] top2 indices (as float), [32768..65535] gates, [65536] aux
// Split-fp16 MFMA (3-term: xh*wh + xh*wl + xl*wh). r5 structure (coalesced
// x -> LDS frag-linear -> b128 reads) with TM=16 / grid=1024 for 4 blocks/CU.
#define NTOK 16384
#define DDIM 2048
#define NEXP 64
#define TM   16                 // tokens per block (1 MFMA M-tile)
#define NBLK (NTOK / TM)        // 1024 blocks -> 4 blocks/CU
#define NCH  32                 // K chunks of 64
#define NS   64                 // K32 MFMA steps total

typedef _Float16 half4v __attribute__((ext_vector_type(4)));
typedef _Float16 half8v __attribute__((ext_vector_type(8)));
typedef float    f32x4  __attribute__((ext_vector_type(4)));

#define MFMA16(a, b, c) __builtin_amdgcn_mfma_f32_16x16x32_f16((a), (b), (c), 0, 0, 0)

// W prep: fp32 -> (wh, wl) fp16 in MFMA-B fragment-linear layout (r5-verified):
// element (e,k): S=k>>5, nb=e>>4, nl=e&15, q=(k>>3)&3, j=k&7
// off = S*2048 + nb*512 + q*128 + nl*8 + j
__global__ __launch_bounds__(256) void prep_kernel(const float* __restrict__ W,
                                                   _Float16* __restrict__ Wh,
                                                   _Float16* __restrict__ Wl,
                                                   float* __restrict__ accg) {
    int idx = blockIdx.x * 256 + threadIdx.x;       // 512 blocks -> 131072
    int e = idx >> 11, k = idx & 2047;
    float w = W[idx];
    _Float16 h = (_Float16)w;
    _Float16 l = (_Float16)(w - (float)h);
    int S = k >> 5, nb = e >> 4, nl = e & 15, q = (k >> 3) & 3, j = k & 7;
    size_t off = (size_t)S * 2048 + nb * 512 + q * 128 + nl * 8 + j;
    Wh[off] = h;
    Wl[off] = l;
    if (blockIdx.x == 0 && threadIdx.x < 128) accg[threadIdx.x] = 0.0f;
}

__device__ inline void cvt_store(_Float16* __restrict__ Hp, _Float16* __restrict__ Lp,
                                 int off, float4 v) {
    half4v h, l;
    h.x = (_Float16)v.x; l.x = (_Float16)(v.x - (float)h.x);
    h.y = (_Float16)v.y; l.y = (_Float16)(v.y - (float)h.y);
    h.z = (_Float16)v.z; l.z = (_Float16)(v.z - (float)h.z);
    h.w = (_Float16)v.w; l.w = (_Float16)(v.w - (float)h.w);
    *(half4v*)&Hp[off] = h;
    *(half4v*)&Lp[off] = l;
}

__global__ __launch_bounds__(256) void router_kernel(
    const float* __restrict__ x, const _Float16* __restrict__ Wh,
    const _Float16* __restrict__ Wl, float* __restrict__ accg,
    float* __restrict__ out)
{
    // A (x) fp16 frag-linear, double-buffered: 2 K32-steps x 64 lanes x 8 halfs
    __shared__ __align__(16) _Float16 Ah[2][1024];   // 4 KB
    __shared__ __align__(16) _Float16 Al[2][1024];   // 4 KB
    __shared__ float lgt[TM][NEXP + 1];              // 4.2 KB
    __shared__ float cnt[NEXP];

    const int tid  = threadIdx.x;
    const int lane = tid & 63;
    const int wv   = __builtin_amdgcn_readfirstlane(tid >> 6);  // expert block 0..3
    const int m0   = blockIdx.x * TM;

    if (tid < NEXP) cnt[tid] = 0.0f;

    // staging map: thread t -> x[tok][kk..kk+3], tok=t>>4 (0..15), kk=(t&15)*4
    const int tok0 = tid >> 4;
    const int kk0  = (tid & 15) * 4;
    const int s0   = kk0 >> 5, q0 = (kk0 >> 3) & 3, j00 = kk0 & 7;
    const int offA = (s0 * 64 + q0 * 16 + tok0) * 8 + j00;

    const float* gx = x + (size_t)(m0 + tok0) * DDIM + kk0;

    // W-frag pointers for this wave's 16 experts (frag-linear, L2-hot)
    const _Float16* whp = Wh + wv * 512 + lane * 8;
    const _Float16* wlp = Wl + wv * 512 + lane * 8;

    f32x4 acc = {0.f, 0.f, 0.f, 0.f};

    // prologue: prefetch x chunks 0,1 and W steps 0,1
    float4 stg[2];
    stg[0] = *(const float4*)(gx);
    stg[1] = *(const float4*)(gx + 64);
    half8v wbh[2], wbl[2];
    #pragma unroll
    for (int s = 0; s < 2; ++s) {
        wbh[s] = *(const half8v*)(whp + (size_t)s * 2048);
        wbl[s] = *(const half8v*)(wlp + (size_t)s * 2048);
    }

    for (int ch = 0; ch < NCH; ++ch) {
        const int p = ch & 1;
        // stage chunk ch -> LDS buf p (fp16 split, frag-linear)
        cvt_store(&Ah[p][0], &Al[p][0], offA, stg[p]);
        // depth-2 x prefetch (wrap reload harmless)
        const int cf = (ch + 2 < NCH) ? ch + 2 : 0;
        stg[p] = *(const float4*)(gx + cf * 64);
        __syncthreads();   // dbuf parity: staging of p never races compute of p^1
        #pragma unroll
        for (int s = 0; s < 2; ++s) {
            const int Sg  = ch * 2 + s;
            const int SgN = (Sg + 2) & (NS - 1);
            half8v ah = *(const half8v*)&Ah[p][(s * 64 + lane) * 8];
            half8v al = *(const half8v*)&Al[p][(s * 64 + lane) * 8];
            half8v bh = wbh[s], bl = wbl[s];
            // prefetch W step Sg+2 into this parity slot
            wbh[s] = *(const half8v*)(whp + (size_t)SgN * 2048);
            wbl[s] = *(const half8v*)(wlp + (size_t)SgN * 2048);
            acc = MFMA16(al, bh, acc);
            acc = MFMA16(ah, bl, acc);
            acc = MFMA16(ah, bh, acc);
        }
    }

    // ---- C layout: row m=(lane>>4)*4+r, col n=lane&15 (m89/r5-verified) ----
    {
        const int q  = lane >> 4;
        const int nl = lane & 15;
        #pragma unroll
        for (int r = 0; r < 4; ++r)
            lgt[q * 4 + r][wv * 16 + nl] = acc[r];
    }
    __syncthreads();

    // ---- softmax + top-2: 8 threads per token (16 tok x 8 = 128 thr) ----
    if (tid < 128) {
        const int m = tid >> 3;
        const int j = tid & 7;
        float l[8];
        #pragma unroll
        for (int i = 0; i < 8; ++i) l[i] = lgt[m][j * 8 + i];

        float mx = l[0];
        #pragma unroll
        for (int i = 1; i < 8; ++i) mx = fmaxf(mx, l[i]);
        #pragma unroll
        for (int off = 1; off < 8; off <<= 1) mx = fmaxf(mx, __shfl_xor(mx, off, 8));

        float ev[8];
        float zs = 0.f;
        float v1 = -INFINITY, v2 = -INFINITY;
        int i1 = 0, i2 = 0;
        #pragma unroll
        for (int i = 0; i < 8; ++i) {
            ev[i] = __expf(l[i] - mx);
            zs += ev[i];
            int e = j * 8 + i;
            if (l[i] > v1)      { v2 = v1; i2 = i1; v1 = l[i]; i1 = e; }
            else if (l[i] > v2) { v2 = l[i]; i2 = e; }
        }
        #pragma unroll
        for (int off = 1; off < 8; off <<= 1) zs += __shfl_xor(zs, off, 8);

        // merge top-2 across 8 lanes (value desc, index asc on ties = lax.top_k)
        #pragma unroll
        for (int off = 1; off < 8; off <<= 1) {
            float ov1 = __shfl_xor(v1, off, 8);
            int   oi1 = __shfl_xor(i1, off, 8);
            float ov2 = __shfl_xor(v2, off, 8);
            int   oi2 = __shfl_xor(i2, off, 8);
            bool afirst = (v1 > ov1) || (v1 == ov1 && i1 < oi1);
            if (afirst) {
                bool t = (v2 > ov1) || (v2 == ov1 && i2 < oi1);
                v2 = t ? v2 : ov1;
                i2 = t ? i2 : oi1;
            } else {
                bool t = (ov2 > v1) || (ov2 == v1 && oi2 < i1);
                v2 = t ? ov2 : v1;
                i2 = t ? oi2 : i1;
                v1 = ov1;
                i1 = oi1;
            }
        }

        const float invz = 1.0f / zs;
        if (j == 0) {
            float p1 = invz;                      // v1 == mx exactly
            float p2 = __expf(v2 - mx) * invz;
            float sden = p1 + p2 + 1e-9f;
            int tok = m0 + m;
            out[tok * 2 + 0] = (float)i1;
            out[tok * 2 + 1] = (float)i2;
            out[32768 + tok * 2 + 0] = p1 / sden;
            out[32768 + tok * 2 + 1] = p2 / sden;
            atomicAdd(&cnt[i1], 1.0f);
            atomicAdd(&cnt[i2], 1.0f);
        }

        // probs writeback (own slots only)
        #pragma unroll
        for (int i = 0; i < 8; ++i) lgt[m][j * 8 + i] = ev[i] * invz;
    }
    __syncthreads();

    // global accumulators (accg zeroed by prep each launch)
    if (tid < NEXP) {
        atomicAdd(&accg[tid], cnt[tid]);
    } else if (tid < 128) {
        int e = tid - 64;
        float s = 0.f;
        #pragma unroll
        for (int t = 0; t < TM; ++t) s += lgt[t][e];
        atomicAdd(&accg[64 + e], s);
    }
}

__global__ void finalize_kernel(const float* __restrict__ accg,
                                float* __restrict__ out)
{
    int t = threadIdx.x;   // 64 threads
    float c = accg[t];
    float p = accg[64 + t];
    float term = (c / (float)(NTOK * 2)) * (p / (float)NTOK);
    #pragma unroll
    for (int off = 1; off < 64; off <<= 1) term += __shfl_xor(term, off, 64);
    if (t == 0) out[65536] = 0.01f * (float)NEXP * term;
}

extern "C" void kernel_launch(void* const* d_in, const int* in_sizes, int n_in,
                              void* d_out, int out_size, void* d_ws, size_t ws_size,
                              hipStream_t stream) {
    const float* x = (const float*)d_in[0];   // [4,4096,2048]
    const float* W = (const float*)d_in[1];   // [64,2048]
    float* out  = (float*)d_out;              // 65537 floats
    float* accg = (float*)d_ws;               // 128 floats
    _Float16* Wh = (_Float16*)(accg + 128);   // 131072 halfs (256 KB)
    _Float16* Wl = Wh + (size_t)DDIM * NEXP;  // 131072 halfs (256 KB)

    prep_kernel<<<512, 256, 0, stream>>>(W, Wh, Wl, accg);
    router_kernel<<<NBLK, 256, 0, stream>>>(x, Wh, Wl, accg, out);
    finalize_kernel<<<1, 64, 0, stream>>>(accg, out);
}